// Round 2
// baseline (4004.077 us; speedup 1.0000x reference)
//
#include <hip/hip_runtime.h>

#define EPS_BN 1e-5f

typedef unsigned int u32;

constexpr int N_IN_C  = 100000;
constexpr int N_OUT_C = 400000;
constexpr int KTAPS   = 27;
constexpr int M_UP_C  = 100000;
constexpr int M_C_C   = 120000;

constexpr int TILE    = 256;                      // output rows per block
constexpr int NTILES  = (N_OUT_C + TILE - 1) / TILE;   // 1563
constexpr int NB      = NTILES * KTAPS;           // 42201 buckets
constexpr int MAXPAIR = KTAPS * M_C_C;            // 3.24M

// ---------------------------------------------------------------------------
// Counting-sort phase 1: histogram of pairs into (out_tile, k) buckets.
// ---------------------------------------------------------------------------
__global__ __launch_bounds__(256) void hist_kernel(
    const int* __restrict__ out_idx, u32* __restrict__ cnt, int M)
{
    const int k = blockIdx.y;
    const int m = blockIdx.x * 256 + threadIdx.x;
    if (m >= M) return;
    const int o = out_idx[(size_t)k * M + m];
    atomicAdd(&cnt[(o >> 8) * KTAPS + k], 1u);
}

// ---------------------------------------------------------------------------
// Phase 2: exclusive scan over NB buckets (single block, 1024 threads).
// Writes starts[0..nb] and a working copy into cursor[].
// ---------------------------------------------------------------------------
__global__ __launch_bounds__(1024) void scan_kernel(
    const u32* __restrict__ cnt, u32* __restrict__ starts,
    u32* __restrict__ cursor, int nb)
{
    __shared__ u32 tmp[1024];
    __shared__ u32 carry_s;
    const int t = threadIdx.x;
    if (t == 0) carry_s = 0;
    __syncthreads();
    for (int base = 0; base < nb; base += 1024) {
        const int i = base + t;
        const u32 v = (i < nb) ? cnt[i] : 0u;
        tmp[t] = v;
        __syncthreads();
        for (int off = 1; off < 1024; off <<= 1) {
            const u32 u = (t >= off) ? tmp[t - off] : 0u;
            __syncthreads();
            tmp[t] += u;
            __syncthreads();
        }
        const u32 cbase = carry_s;
        if (i < nb) {
            const u32 e = cbase + tmp[t] - v;
            starts[i] = e;
            cursor[i] = e;
        }
        const u32 total = tmp[1023];
        __syncthreads();
        if (t == 0) carry_s = cbase + total;
        __syncthreads();
    }
    if (t == 0) starts[nb] = carry_s;
}

// ---------------------------------------------------------------------------
// Phase 3: scatter pairs into their bucket segment.
// Entry pack: (in_idx << 8) | (out & 255)   [in < 2^19, so fits 27 bits]
// ---------------------------------------------------------------------------
__global__ __launch_bounds__(256) void fill_kernel(
    const int* __restrict__ in_idx, const int* __restrict__ out_idx,
    u32* __restrict__ cursor, u32* __restrict__ entries, int M)
{
    const int k = blockIdx.y;
    const int m = blockIdx.x * 256 + threadIdx.x;
    if (m >= M) return;
    const int o  = out_idx[(size_t)k * M + m];
    const int in = in_idx[(size_t)k * M + m];
    const u32 pos = atomicAdd(&cursor[(o >> 8) * KTAPS + k], 1u);
    entries[pos] = ((u32)in << 8) | (u32)(o & 255);
}

// ---------------------------------------------------------------------------
// Tile conv: one block per 256-row output tile. Loops k = 0..26 with that
// tap's weight half-slice in VGPRs. Wave layout: lane = (c in [0,32), h);
// h in {0,1} splits the input-channel dim (K-split): h=0 handles xa channels,
// h=1 handles xb channels, combined with a shfl_xor(32). Accumulation into a
// 32 KB LDS tile via ds-atomics (banks 0..31, conflict-free), then one
// coalesced write of the tile + fused BN partial stats.
//   CINH: channels per half (32 for Cin=64, 16 for Cin=32).
//   w layout: [K][2*CINH][32].
// ---------------------------------------------------------------------------
template <int CINH>
__global__ __launch_bounds__(256) void conv_tile(
    const float* __restrict__ xa, int lda,
    const float* __restrict__ xb, int ldb,
    const float* __restrict__ w,
    const u32*   __restrict__ entries,
    const u32*   __restrict__ starts,
    float*       __restrict__ dest,
    float*       __restrict__ stats,
    int n_out)
{
    __shared__ float sacc[TILE * 32];   // 32 KB

    const int tile = blockIdx.x;
    const int lane = threadIdx.x & 63;
    const int wid  = threadIdx.x >> 6;   // 0..3
    const int c    = lane & 31;
    const int h    = lane >> 5;

    for (int i = threadIdx.x; i < TILE * 32; i += 256) sacc[i] = 0.f;
    __syncthreads();

    const float* base = h ? xb : xa;
    const int    ld   = h ? ldb : lda;

    for (int k = 0; k < KTAPS; ++k) {
        float wreg[CINH];
        const float* wk = w + ((size_t)k * (2 * CINH) + h * CINH) * 32 + c;
#pragma unroll
        for (int j = 0; j < CINH; ++j) wreg[j] = wk[j * 32];

        const int b    = tile * KTAPS + k;
        const int seg0 = (int)starts[b];
        const int seg1 = (int)starts[b + 1];

        for (int i = seg0 + wid; i < seg1; i += 4) {
            const u32 e  = entries[i];
            const int in = (int)(e >> 8);
            const int ol = (int)(e & 255u);
            const float* r = base + (size_t)in * ld;
            float a = 0.f;
#pragma unroll
            for (int q = 0; q < CINH / 4; ++q) {
                const float4 v = *reinterpret_cast<const float4*>(r + q * 4);
                a = fmaf(v.x, wreg[q * 4 + 0], a);
                a = fmaf(v.y, wreg[q * 4 + 1], a);
                a = fmaf(v.z, wreg[q * 4 + 2], a);
                a = fmaf(v.w, wreg[q * 4 + 3], a);
            }
            a += __shfl_xor(a, 32);
            if (h == 0) atomicAdd(&sacc[ol * 32 + c], a);
        }
        __syncthreads();   // wreg reload next k is fine; sync protects nothing
                           // structurally but keeps segments from racing far
    }
    __syncthreads();

    // Write tile (coalesced) + fused BN partial stats.
    const int row0  = tile * TILE;
    const int nrows = min(TILE, n_out - row0);
    float s = 0.f, q = 0.f;
    for (int i = threadIdx.x; i < nrows * 32; i += 256) {
        const float v = sacc[i];
        dest[(size_t)row0 * 32 + i] = v;
        s += v;
        q = fmaf(v, v, q);
    }
    __syncthreads();
    sacc[threadIdx.x]       = s;
    sacc[256 + threadIdx.x] = q;
    __syncthreads();
    if (threadIdx.x < 32) {
        float ts = 0.f, tq = 0.f;
#pragma unroll
        for (int g = 0; g < 8; ++g) {
            ts += sacc[threadIdx.x + 32 * g];
            tq += sacc[256 + threadIdx.x + 32 * g];
        }
        atomicAdd(&stats[threadIdx.x], ts);
        atomicAdd(&stats[32 + threadIdx.x], tq);
    }
}

// ---------------------------------------------------------------------------
// y = relu((x - mean) * rsqrt(var + eps) * g + bt)
// ---------------------------------------------------------------------------
__global__ __launch_bounds__(256) void bn_relu_kernel(
    const float* __restrict__ hsrc,
    const float* __restrict__ stats,
    const float* __restrict__ g,
    const float* __restrict__ bt,
    float* __restrict__ dst, int n)
{
    const int t = blockIdx.x * 256 + threadIdx.x;
    if (t >= n * 32) return;
    const int c = t & 31;
    const float invn = 1.f / (float)n;
    const float m    = stats[c] * invn;
    const float var  = fmaxf(stats[32 + c] * invn - m * m, 0.f);
    const float inv  = rsqrtf(var + EPS_BN);
    float v = (hsrc[t] - m) * inv * g[c] + bt[c];
    dst[t] = v > 0.f ? v : 0.f;
}

// ---------------------------------------------------------------------------
extern "C" void kernel_launch(void* const* d_in, const int* in_sizes, int n_in,
                              void* d_out, int out_size, void* d_ws, size_t ws_size,
                              hipStream_t stream)
{
    const float* x      = (const float*)d_in[0];
    const float* x_skip = (const float*)d_in[1];
    const float* w_up   = (const float*)d_in[2];
    // d_in[3] = b_up: cancels exactly through train-mode BN -> unused.
    const float* g_up   = (const float*)d_in[4];
    const float* bt_up  = (const float*)d_in[5];
    const float* w1     = (const float*)d_in[6];
    const float* g1     = (const float*)d_in[7];
    const float* bt1    = (const float*)d_in[8];
    const float* w2     = (const float*)d_in[9];
    const float* g2     = (const float*)d_in[10];
    const float* bt2    = (const float*)d_in[11];
    const int* up_in    = (const int*)d_in[12];
    const int* up_out   = (const int*)d_in[13];
    const int* c1_in    = (const int*)d_in[14];
    const int* c1_out   = (const int*)d_in[15];
    const int* c2_in    = (const int*)d_in[16];
    const int* c2_out   = (const int*)d_in[17];

    float* A      = (float*)d_ws;                     // [N_OUT*32] intermediate
    float* stats  = A + (size_t)N_OUT_C * 32;         // 192 floats (3 x 64)
    u32*   cnt    = (u32*)(stats + 192);              // [NB]
    u32*   starts = cnt + NB;                         // [NB+1]
    u32*   cursor = starts + NB + 1;                  // [NB]
    u32*   entries= cursor + NB;                      // [MAXPAIR]

    float* out = (float*)d_out;
    const dim3 blk(256);
    const int elem_blocks = (N_OUT_C * 32 + 255) / 256;
    const dim3 gUp((M_UP_C + 255) / 256, KTAPS);
    const dim3 gC ((M_C_C  + 255) / 256, KTAPS);

    hipMemsetAsync(stats, 0, 192 * sizeof(float), stream);

    // ---- stage 1: up conv  x[100k,64] -> A raw, then BN+ReLU in place ----
    hipMemsetAsync(cnt, 0, NB * sizeof(u32), stream);
    hist_kernel<<<gUp, blk, 0, stream>>>(up_out, cnt, M_UP_C);
    scan_kernel<<<1, 1024, 0, stream>>>(cnt, starts, cursor, NB);
    fill_kernel<<<gUp, blk, 0, stream>>>(up_in, up_out, cursor, entries, M_UP_C);
    conv_tile<32><<<NTILES, blk, 0, stream>>>(
        x, 64, x + 32, 64, w_up, entries, starts, A, stats, N_OUT_C);
    bn_relu_kernel<<<elem_blocks, blk, 0, stream>>>(A, stats, g_up, bt_up, A, N_OUT_C);

    // ---- stage 2: conv1 concat([A, x_skip]) -> d_out raw, BN+ReLU -> A ----
    hipMemsetAsync(cnt, 0, NB * sizeof(u32), stream);
    hist_kernel<<<gC, blk, 0, stream>>>(c1_out, cnt, M_C_C);
    scan_kernel<<<1, 1024, 0, stream>>>(cnt, starts, cursor, NB);
    fill_kernel<<<gC, blk, 0, stream>>>(c1_in, c1_out, cursor, entries, M_C_C);
    conv_tile<32><<<NTILES, blk, 0, stream>>>(
        A, 32, x_skip, 32, w1, entries, starts, out, stats + 64, N_OUT_C);
    bn_relu_kernel<<<elem_blocks, blk, 0, stream>>>(out, stats + 64, g1, bt1, A, N_OUT_C);

    // ---- stage 3: conv2 A -> d_out raw, BN+ReLU in place ----
    hipMemsetAsync(cnt, 0, NB * sizeof(u32), stream);
    hist_kernel<<<gC, blk, 0, stream>>>(c2_out, cnt, M_C_C);
    scan_kernel<<<1, 1024, 0, stream>>>(cnt, starts, cursor, NB);
    fill_kernel<<<gC, blk, 0, stream>>>(c2_in, c2_out, cursor, entries, M_C_C);
    conv_tile<16><<<NTILES, blk, 0, stream>>>(
        A, 32, A + 16, 32, w2, entries, starts, out, stats + 128, N_OUT_C);
    bn_relu_kernel<<<elem_blocks, blk, 0, stream>>>(out, stats + 128, g2, bt2, out, N_OUT_C);
}

// Round 3
// 3387.214 us; speedup vs baseline: 1.1821x; 1.1821x over previous
//
#include <hip/hip_runtime.h>

#define EPS_BN 1e-5f

typedef unsigned int u32;
typedef short short8 __attribute__((ext_vector_type(8)));
typedef float f32x16 __attribute__((ext_vector_type(16)));

constexpr int N_IN_C  = 100000;
constexpr int N_OUT_C = 400000;
constexpr int KTAPS   = 27;
constexpr int M_UP_C  = 100000;
constexpr int M_C_C   = 120000;

constexpr int TILE    = 256;
constexpr int NTILES  = (N_OUT_C + TILE - 1) / TILE;   // 1563
constexpr int NB      = NTILES * KTAPS;                // 42201
constexpr int MAXPAIR = KTAPS * M_C_C;                 // 3.24M

__device__ inline unsigned short f2bf(float f) {
    u32 u = __builtin_bit_cast(u32, f);
    u32 r = (u + 0x7FFFu + ((u >> 16) & 1u)) >> 16;
    return (unsigned short)r;
}

// ---------------------------------------------------------------------------
// f32 -> bf16 dense convert (float4 -> ushort4 per thread)
// ---------------------------------------------------------------------------
__global__ __launch_bounds__(256) void cvt_bf16_kernel(
    const float* __restrict__ s, ushort* __restrict__ d, int n4)
{
    const int i = blockIdx.x * 256 + threadIdx.x;
    if (i >= n4) return;
    const float4 v = reinterpret_cast<const float4*>(s)[i];
    ushort4 o;
    o.x = f2bf(v.x); o.y = f2bf(v.y); o.z = f2bf(v.z); o.w = f2bf(v.w);
    reinterpret_cast<ushort4*>(d)[i] = o;
}

// ---------------------------------------------------------------------------
// Pack all three weight tensors into MFMA B-fragment layout, bf16.
// frag[tap][f][lane][j] = W[tap][k = 16f + 8*(lane>>5) + j][lane&31]
// ---------------------------------------------------------------------------
__global__ __launch_bounds__(256) void wpack_kernel(
    const float* __restrict__ wU, const float* __restrict__ w1,
    const float* __restrict__ w2,
    ushort* __restrict__ fU, ushort* __restrict__ f1, ushort* __restrict__ f2)
{
    const int t = blockIdx.x * 256 + threadIdx.x;
    const float* w; ushort* dst; int CIN, NF, local;
    if      (t <  6912) { w = wU; dst = fU; CIN = 64; NF = 4; local = t; }
    else if (t < 13824) { w = w1; dst = f1; CIN = 64; NF = 4; local = t - 6912; }
    else if (t < 17280) { w = w2; dst = f2; CIN = 32; NF = 2; local = t - 13824; }
    else return;
    const int lane = local & 63;
    const int fi   = (local >> 6) % NF;
    const int tap  = local / (64 * NF);
    const int half = lane >> 5, colc = lane & 31;
    ushort* o = dst + ((size_t)(tap * NF + fi) * 64 + lane) * 8;
#pragma unroll
    for (int j = 0; j < 8; ++j) {
        const int k = 16 * fi + 8 * half + j;
        o[j] = f2bf(w[((size_t)tap * CIN + k) * 32 + colc]);
    }
}

// ---------------------------------------------------------------------------
// Counting sort: histogram -> scan -> fill. Buckets = (out>>8)*27 + k.
// ---------------------------------------------------------------------------
__global__ __launch_bounds__(256) void hist_kernel(
    const int* __restrict__ out_idx, u32* __restrict__ cnt, int M)
{
    const int k = blockIdx.y;
    const int m = blockIdx.x * 256 + threadIdx.x;
    if (m >= M) return;
    const int o = out_idx[(size_t)k * M + m];
    atomicAdd(&cnt[(o >> 8) * KTAPS + k], 1u);
}

__global__ __launch_bounds__(1024) void scan_kernel(
    const u32* __restrict__ cnt, u32* __restrict__ starts,
    u32* __restrict__ cursor, int nb)
{
    __shared__ u32 part[1024];
    const int t = threadIdx.x;
    const int per = (nb + 1023) / 1024;
    const int b0 = t * per;
    const int b1 = min(b0 + per, nb);
    u32 s = 0;
    for (int i = b0; i < b1; ++i) s += cnt[i];
    part[t] = s;
    __syncthreads();
    for (int off = 1; off < 1024; off <<= 1) {
        const u32 v = (t >= off) ? part[t - off] : 0u;
        __syncthreads();
        part[t] += v;
        __syncthreads();
    }
    u32 run = (t == 0) ? 0u : part[t - 1];
    for (int i = b0; i < b1; ++i) {
        const u32 c = cnt[i];
        starts[i] = run; cursor[i] = run;
        run += c;
    }
    if (t == 1023) starts[nb] = run;
}

__global__ __launch_bounds__(256) void fill_kernel(
    const int* __restrict__ in_idx, const int* __restrict__ out_idx,
    u32* __restrict__ cursor, u32* __restrict__ entries, int M)
{
    const int k = blockIdx.y;
    const int m = blockIdx.x * 256 + threadIdx.x;
    if (m >= M) return;
    const int o  = out_idx[(size_t)k * M + m];
    const int in = in_idx[(size_t)k * M + m];
    const u32 pos = atomicAdd(&cursor[(o >> 8) * KTAPS + k], 1u);
    entries[pos] = ((u32)in << 8) | (u32)(o & 255);
}

// ---------------------------------------------------------------------------
// MFMA tile conv. One block per 256-row output tile; 4 waves; wave w handles
// taps w, w+4, ... Per batch of 32 entries: lane (l&31) owns one entry, lane
// half (l>>5) owns one 8-elem k-segment per fragment. NF = Cin/16 fragments
// of mfma_f32_32x32x16_bf16. C rows map back to entries; scatter into a
// 32 KB LDS fp32 tile via ds_add (2 lanes/bank = conflict-free). Fused BN
// partial stats on the coalesced tile write.
// ---------------------------------------------------------------------------
template <int NF, bool SPLIT>
__global__ __launch_bounds__(256) void conv_mfma(
    const ushort* __restrict__ srcA, int rbA,
    const ushort* __restrict__ srcB, int rbB,
    const ushort* __restrict__ wfrag,
    const u32*   __restrict__ entries,
    const u32*   __restrict__ starts,
    float*       __restrict__ dest,
    float*       __restrict__ stats,
    int n_out)
{
    __shared__ float sacc[TILE * 32];   // 32 KB

    const int tile = blockIdx.x;
    const int tid  = threadIdx.x;
    const int lane = tid & 63;
    const int wid  = tid >> 6;
    const int col  = lane & 31;
    const int half = lane >> 5;

    for (int i = tid; i < TILE * 32; i += 256) sacc[i] = 0.f;
    __syncthreads();

    const short8* wf8 = reinterpret_cast<const short8*>(wfrag);

    for (int tap = wid; tap < KTAPS; tap += 4) {
        short8 bf[NF];
#pragma unroll
        for (int f = 0; f < NF; ++f) bf[f] = wf8[(tap * NF + f) * 64 + lane];

        const int b  = tile * KTAPS + tap;
        const int s0 = (int)starts[b];
        const int s1 = (int)starts[b + 1];

        for (int bb = s0; bb < s1; bb += 32) {
            const int  ei    = bb + col;
            const bool valid = (ei < s1);
            const u32  e     = valid ? entries[ei] : 0u;
            const int  in    = (int)(e >> 8);
            const int  olb   = (int)(e & 255u) << 7;   // byte offset of out row

            short8 af[NF];
#pragma unroll
            for (int f = 0; f < NF; ++f) {
                const char* base;
                int off;
                if (SPLIT && f >= NF / 2) {
                    base = (const char*)srcB;
                    off  = in * rbB + (f - NF / 2) * 32 + half * 16;
                } else {
                    base = (const char*)srcA;
                    off  = in * rbA + f * 32 + half * 16;
                }
                short8 z = {0, 0, 0, 0, 0, 0, 0, 0};
                af[f] = valid ? *reinterpret_cast<const short8*>(base + off) : z;
            }

            f32x16 acc;
#pragma unroll
            for (int r = 0; r < 16; ++r) acc[r] = 0.f;
#pragma unroll
            for (int f = 0; f < NF; ++f)
                acc = __builtin_amdgcn_mfma_f32_32x32x16_bf16(af[f], bf[f], acc, 0, 0, 0);

#pragma unroll
            for (int r = 0; r < 16; ++r) {
                const int row = (r & 3) + 8 * (r >> 2) + 4 * half;
                const int ob  = __shfl(olb, row);
                atomicAdd(reinterpret_cast<float*>(
                              reinterpret_cast<char*>(sacc) + ob + (col << 2)),
                          acc[r]);
            }
        }
    }
    __syncthreads();

    // Coalesced tile write + fused BN partial stats.
    const int row0  = tile * TILE;
    const int nrows = min(TILE, n_out - row0);
    float s = 0.f, q = 0.f;
    for (int i = tid; i < nrows * 32; i += 256) {
        const float v = sacc[i];
        dest[(size_t)row0 * 32 + i] = v;
        s += v;
        q = fmaf(v, v, q);
    }
    __syncthreads();
    sacc[tid]       = s;
    sacc[256 + tid] = q;
    __syncthreads();
    if (tid < 32) {
        float ts = 0.f, tq = 0.f;
#pragma unroll
        for (int g = 0; g < 8; ++g) {
            ts += sacc[tid + 32 * g];
            tq += sacc[256 + tid + 32 * g];
        }
        atomicAdd(&stats[tid], ts);
        atomicAdd(&stats[32 + tid], tq);
    }
}

// ---------------------------------------------------------------------------
// y = relu((x-mean)*rsqrt(var+eps)*g + bt); dst bf16 (intermediate) or f32.
// One float4 per thread.
// ---------------------------------------------------------------------------
template <bool BF16OUT>
__global__ __launch_bounds__(256) void bn_relu_kernel(
    const float* __restrict__ h,
    const float* __restrict__ stats,
    const float* __restrict__ g,
    const float* __restrict__ bt,
    void* __restrict__ dst, int n)
{
    const int i = blockIdx.x * 256 + threadIdx.x;
    if (i >= n * 8) return;
    const float4 v = reinterpret_cast<const float4*>(h)[i];
    const int c0 = (i & 7) * 4;
    const float invn = 1.f / (float)n;
    float o[4];
    const float vin[4] = {v.x, v.y, v.z, v.w};
#pragma unroll
    for (int j = 0; j < 4; ++j) {
        const int c   = c0 + j;
        const float m   = stats[c] * invn;
        const float var = fmaxf(stats[32 + c] * invn - m * m, 0.f);
        const float sc  = rsqrtf(var + EPS_BN) * g[c];
        float y = (vin[j] - m) * sc + bt[c];
        o[j] = y > 0.f ? y : 0.f;
    }
    if (BF16OUT) {
        ushort4 w;
        w.x = f2bf(o[0]); w.y = f2bf(o[1]); w.z = f2bf(o[2]); w.w = f2bf(o[3]);
        reinterpret_cast<ushort4*>(dst)[i] = w;
    } else {
        float4 w = {o[0], o[1], o[2], o[3]};
        reinterpret_cast<float4*>(dst)[i] = w;
    }
}

// ---------------------------------------------------------------------------
extern "C" void kernel_launch(void* const* d_in, const int* in_sizes, int n_in,
                              void* d_out, int out_size, void* d_ws, size_t ws_size,
                              hipStream_t stream)
{
    const float* x      = (const float*)d_in[0];
    const float* x_skip = (const float*)d_in[1];
    const float* w_up   = (const float*)d_in[2];
    // d_in[3] = b_up cancels exactly through train-mode BN -> unused.
    const float* g_up   = (const float*)d_in[4];
    const float* bt_up  = (const float*)d_in[5];
    const float* w1     = (const float*)d_in[6];
    const float* g1     = (const float*)d_in[7];
    const float* bt1    = (const float*)d_in[8];
    const float* w2     = (const float*)d_in[9];
    const float* g2     = (const float*)d_in[10];
    const float* bt2    = (const float*)d_in[11];
    const int* up_in    = (const int*)d_in[12];
    const int* up_out   = (const int*)d_in[13];
    const int* c1_in    = (const int*)d_in[14];
    const int* c1_out   = (const int*)d_in[15];
    const int* c2_in    = (const int*)d_in[16];
    const int* c2_out   = (const int*)d_in[17];

    // workspace carve (all 16B-aligned)
    ushort* h16    = (ushort*)d_ws;                       // [400000*32]
    ushort* xb16   = h16  + (size_t)N_OUT_C * 32;         // [100000*64]
    ushort* skip16 = xb16 + (size_t)N_IN_C * 64;          // [400000*32]
    ushort* wfU    = skip16 + (size_t)N_OUT_C * 32;       // 27*4*64*8
    ushort* wf1    = wfU + 27 * 4 * 64 * 8;
    ushort* wf2    = wf1 + 27 * 4 * 64 * 8;               // 27*2*64*8
    float*  stats  = (float*)(wf2 + 27 * 2 * 64 * 8);     // 192
    u32*    cnt    = (u32*)(stats + 192);                 // [NB]
    u32*    starts = cnt + NB;                            // [NB+1]
    u32*    cursor = starts + NB + 1;                     // [NB]
    u32*    entries= cursor + NB;                         // [MAXPAIR]

    float* out = (float*)d_out;
    const dim3 blk(256);
    const dim3 gUp((M_UP_C + 255) / 256, KTAPS);
    const dim3 gC ((M_C_C  + 255) / 256, KTAPS);
    const int bn_blocks = (N_OUT_C * 8 + 255) / 256;

    hipMemsetAsync(stats, 0, 192 * sizeof(float), stream);

    // prep: bf16 copies of gather sources + weight fragments
    cvt_bf16_kernel<<<(N_IN_C * 16 + 255) / 256, blk, 0, stream>>>(x, xb16, N_IN_C * 16);
    cvt_bf16_kernel<<<(N_OUT_C * 8 + 255) / 256, blk, 0, stream>>>(x_skip, skip16, N_OUT_C * 8);
    wpack_kernel<<<(17280 + 255) / 256, blk, 0, stream>>>(w_up, w1, w2, wfU, wf1, wf2);

    // ---- stage 1: up conv  (Cin=64 from xb16) -> d_out raw, BN+ReLU -> h16
    hipMemsetAsync(cnt, 0, NB * sizeof(u32), stream);
    hist_kernel<<<gUp, blk, 0, stream>>>(up_out, cnt, M_UP_C);
    scan_kernel<<<1, 1024, 0, stream>>>(cnt, starts, cursor, NB);
    fill_kernel<<<gUp, blk, 0, stream>>>(up_in, up_out, cursor, entries, M_UP_C);
    conv_mfma<4, false><<<NTILES, blk, 0, stream>>>(
        xb16, 128, xb16, 128, wfU, entries, starts, out, stats, N_OUT_C);
    bn_relu_kernel<true><<<bn_blocks, blk, 0, stream>>>(out, stats, g_up, bt_up, h16, N_OUT_C);

    // ---- stage 2: conv1 (Cin=64 = concat(h16, skip16)) -> d_out raw, BN+ReLU -> h16
    hipMemsetAsync(cnt, 0, NB * sizeof(u32), stream);
    hist_kernel<<<gC, blk, 0, stream>>>(c1_out, cnt, M_C_C);
    scan_kernel<<<1, 1024, 0, stream>>>(cnt, starts, cursor, NB);
    fill_kernel<<<gC, blk, 0, stream>>>(c1_in, c1_out, cursor, entries, M_C_C);
    conv_mfma<4, true><<<NTILES, blk, 0, stream>>>(
        h16, 64, skip16, 64, wf1, entries, starts, out, stats + 64, N_OUT_C);
    bn_relu_kernel<true><<<bn_blocks, blk, 0, stream>>>(out, stats + 64, g1, bt1, h16, N_OUT_C);

    // ---- stage 3: conv2 (Cin=32 from h16) -> d_out raw, BN+ReLU in place (f32)
    hipMemsetAsync(cnt, 0, NB * sizeof(u32), stream);
    hist_kernel<<<gC, blk, 0, stream>>>(c2_out, cnt, M_C_C);
    scan_kernel<<<1, 1024, 0, stream>>>(cnt, starts, cursor, NB);
    fill_kernel<<<gC, blk, 0, stream>>>(c2_in, c2_out, cursor, entries, M_C_C);
    conv_mfma<2, false><<<NTILES, blk, 0, stream>>>(
        h16, 64, h16, 64, wf2, entries, starts, out, stats + 128, N_OUT_C);
    bn_relu_kernel<false><<<bn_blocks, blk, 0, stream>>>(out, stats + 128, g2, bt2, out, N_OUT_C);
}

// Round 4
// 3386.566 us; speedup vs baseline: 1.1823x; 1.0002x over previous
//
#include <hip/hip_runtime.h>

#define EPS_BN 1e-5f

typedef unsigned int u32;
typedef short short8 __attribute__((ext_vector_type(8)));
typedef float f32x16 __attribute__((ext_vector_type(16)));

constexpr int N_IN_C  = 100000;
constexpr int N_OUT_C = 400000;
constexpr int KTAPS   = 27;
constexpr int M_UP_C  = 100000;
constexpr int M_C_C   = 120000;

constexpr int TILE    = 256;
constexpr int NTILES  = (N_OUT_C + TILE - 1) / TILE;   // 1563
constexpr int NB      = NTILES * KTAPS;                // 42201
constexpr int MAXPAIR = KTAPS * M_C_C;                 // 3.24M

__device__ inline unsigned short f2bf(float f) {
    u32 u = __builtin_bit_cast(u32, f);
    u32 r = (u + 0x7FFFu + ((u >> 16) & 1u)) >> 16;
    return (unsigned short)r;
}

// ---------------------------------------------------------------------------
// f32 -> bf16 dense convert (float4 -> ushort4 per thread)
// ---------------------------------------------------------------------------
__global__ __launch_bounds__(256) void cvt_bf16_kernel(
    const float* __restrict__ s, ushort* __restrict__ d, int n4)
{
    const int i = blockIdx.x * 256 + threadIdx.x;
    if (i >= n4) return;
    const float4 v = reinterpret_cast<const float4*>(s)[i];
    ushort4 o;
    o.x = f2bf(v.x); o.y = f2bf(v.y); o.z = f2bf(v.z); o.w = f2bf(v.w);
    reinterpret_cast<ushort4*>(d)[i] = o;
}

// ---------------------------------------------------------------------------
// Pack all three weight tensors into MFMA B-fragment layout, bf16.
// frag[tap][f][lane][j] = W[tap][k = 16f + 8*(lane>>5) + j][lane&31]
// ---------------------------------------------------------------------------
__global__ __launch_bounds__(256) void wpack_kernel(
    const float* __restrict__ wU, const float* __restrict__ w1,
    const float* __restrict__ w2,
    ushort* __restrict__ fU, ushort* __restrict__ f1, ushort* __restrict__ f2)
{
    const int t = blockIdx.x * 256 + threadIdx.x;
    const float* w; ushort* dst; int CIN, NF, local;
    if      (t <  6912) { w = wU; dst = fU; CIN = 64; NF = 4; local = t; }
    else if (t < 13824) { w = w1; dst = f1; CIN = 64; NF = 4; local = t - 6912; }
    else if (t < 17280) { w = w2; dst = f2; CIN = 32; NF = 2; local = t - 13824; }
    else return;
    const int lane = local & 63;
    const int fi   = (local >> 6) % NF;
    const int tap  = local / (64 * NF);
    const int half = lane >> 5, colc = lane & 31;
    ushort* o = dst + ((size_t)(tap * NF + fi) * 64 + lane) * 8;
#pragma unroll
    for (int j = 0; j < 8; ++j) {
        const int k = 16 * fi + 8 * half + j;
        o[j] = f2bf(w[((size_t)tap * CIN + k) * 32 + colc]);
    }
}

// ---------------------------------------------------------------------------
// Counting sort: histogram -> scan -> fill. Buckets = (out>>8)*27 + k.
// ---------------------------------------------------------------------------
__global__ __launch_bounds__(256) void hist_kernel(
    const int* __restrict__ out_idx, u32* __restrict__ cnt, int M)
{
    const int k = blockIdx.y;
    const int m = blockIdx.x * 256 + threadIdx.x;
    if (m >= M) return;
    const int o = out_idx[(size_t)k * M + m];
    atomicAdd(&cnt[(o >> 8) * KTAPS + k], 1u);
}

__global__ __launch_bounds__(1024) void scan_kernel(
    const u32* __restrict__ cnt, u32* __restrict__ starts,
    u32* __restrict__ cursor, int nb)
{
    __shared__ u32 part[1024];
    const int t = threadIdx.x;
    const int per = (nb + 1023) / 1024;
    const int b0 = t * per;
    const int b1 = min(b0 + per, nb);
    u32 s = 0;
    for (int i = b0; i < b1; ++i) s += cnt[i];
    part[t] = s;
    __syncthreads();
    for (int off = 1; off < 1024; off <<= 1) {
        const u32 v = (t >= off) ? part[t - off] : 0u;
        __syncthreads();
        part[t] += v;
        __syncthreads();
    }
    u32 run = (t == 0) ? 0u : part[t - 1];
    for (int i = b0; i < b1; ++i) {
        const u32 c = cnt[i];
        starts[i] = run; cursor[i] = run;
        run += c;
    }
    if (t == 1023) starts[nb] = run;
}

__global__ __launch_bounds__(256) void fill_kernel(
    const int* __restrict__ in_idx, const int* __restrict__ out_idx,
    u32* __restrict__ cursor, u32* __restrict__ entries, int M)
{
    const int k = blockIdx.y;
    const int m = blockIdx.x * 256 + threadIdx.x;
    if (m >= M) return;
    const int o  = out_idx[(size_t)k * M + m];
    const int in = in_idx[(size_t)k * M + m];
    const u32 pos = atomicAdd(&cursor[(o >> 8) * KTAPS + k], 1u);
    entries[pos] = ((u32)in << 8) | (u32)(o & 255);
}

// ---------------------------------------------------------------------------
// MFMA tile conv. One block per 256-row output tile; 4 waves; wave w handles
// taps w, w+4, ... Per batch of 32 entries: lane (l&31) owns one entry, lane
// half (l>>5) owns one 8-elem k-segment per fragment. NF = Cin/16 fragments
// of mfma_f32_32x32x16_bf16. C rows map back to entries; scatter into a
// 32 KB LDS fp32 tile via ds_add_f32 (direct __shared__ indexing so the
// address-space is provably LDS -> no flat atomics). 2 lanes/bank = free.
// ---------------------------------------------------------------------------
template <int NF, bool SPLIT>
__global__ __launch_bounds__(256) void conv_mfma(
    const ushort* __restrict__ srcA, int rbA,
    const ushort* __restrict__ srcB, int rbB,
    const ushort* __restrict__ wfrag,
    const u32*   __restrict__ entries,
    const u32*   __restrict__ starts,
    float*       __restrict__ dest,
    float*       __restrict__ stats,
    int n_out)
{
    __shared__ float sacc[TILE * 32];   // 32 KB

    const int tile = blockIdx.x;
    const int tid  = threadIdx.x;
    const int lane = tid & 63;
    const int wid  = tid >> 6;
    const int col  = lane & 31;
    const int half = lane >> 5;

    for (int i = tid; i < TILE * 32; i += 256) sacc[i] = 0.f;
    __syncthreads();

    const short8* wf8 = reinterpret_cast<const short8*>(wfrag);

    for (int tap = wid; tap < KTAPS; tap += 4) {
        short8 bf[NF];
#pragma unroll
        for (int f = 0; f < NF; ++f) bf[f] = wf8[(tap * NF + f) * 64 + lane];

        const int b  = tile * KTAPS + tap;
        const int s0 = (int)starts[b];
        const int s1 = (int)starts[b + 1];

        for (int bb = s0; bb < s1; bb += 32) {
            const int  ei    = bb + col;
            const bool valid = (ei < s1);
            const u32  e     = valid ? entries[ei] : 0u;
            const int  in    = (int)(e >> 8);
            const int  oli   = (int)(e & 255u) << 5;   // float index of out row

            short8 af[NF];
#pragma unroll
            for (int f = 0; f < NF; ++f) {
                const ushort* base;
                int off;   // in ushort elements
                if (SPLIT && f >= NF / 2) {
                    base = srcB;
                    off  = in * rbB + (f - NF / 2) * 16 + half * 8;
                } else {
                    base = srcA;
                    off  = in * rbA + f * 16 + half * 8;
                }
                short8 z = {0, 0, 0, 0, 0, 0, 0, 0};
                af[f] = valid ? *reinterpret_cast<const short8*>(base + off) : z;
            }

            f32x16 acc;
#pragma unroll
            for (int r = 0; r < 16; ++r) acc[r] = 0.f;
#pragma unroll
            for (int f = 0; f < NF; ++f)
                acc = __builtin_amdgcn_mfma_f32_32x32x16_bf16(af[f], bf[f], acc, 0, 0, 0);

#pragma unroll
            for (int r = 0; r < 16; ++r) {
                const int row = (r & 3) + 8 * (r >> 2) + 4 * half;
                const int oi  = __shfl(oli, row);      // float row base in sacc
                atomicAdd(&sacc[oi + col], acc[r]);    // ds_add_f32
            }
        }
    }
    __syncthreads();

    // Coalesced tile write + fused BN partial stats.
    const int row0  = tile * TILE;
    const int nrows = min(TILE, n_out - row0);
    float s = 0.f, q = 0.f;
    for (int i = tid; i < nrows * 32; i += 256) {
        const float v = sacc[i];
        dest[(size_t)row0 * 32 + i] = v;
        s += v;
        q = fmaf(v, v, q);
    }
    __syncthreads();
    sacc[tid]       = s;
    sacc[256 + tid] = q;
    __syncthreads();
    if (tid < 32) {
        float ts = 0.f, tq = 0.f;
#pragma unroll
        for (int g = 0; g < 8; ++g) {
            ts += sacc[tid + 32 * g];
            tq += sacc[256 + tid + 32 * g];
        }
        atomicAdd(&stats[tid], ts);
        atomicAdd(&stats[32 + tid], tq);
    }
}

// ---------------------------------------------------------------------------
// y = relu((x-mean)*rsqrt(var+eps)*g + bt); dst bf16 (intermediate) or f32.
// One float4 per thread.
// ---------------------------------------------------------------------------
template <bool BF16OUT>
__global__ __launch_bounds__(256) void bn_relu_kernel(
    const float* __restrict__ h,
    const float* __restrict__ stats,
    const float* __restrict__ g,
    const float* __restrict__ bt,
    void* __restrict__ dst, int n)
{
    const int i = blockIdx.x * 256 + threadIdx.x;
    if (i >= n * 8) return;
    const float4 v = reinterpret_cast<const float4*>(h)[i];
    const int c0 = (i & 7) * 4;
    const float invn = 1.f / (float)n;
    float o[4];
    const float vin[4] = {v.x, v.y, v.z, v.w};
#pragma unroll
    for (int j = 0; j < 4; ++j) {
        const int c   = c0 + j;
        const float m   = stats[c] * invn;
        const float var = fmaxf(stats[32 + c] * invn - m * m, 0.f);
        const float sc  = rsqrtf(var + EPS_BN) * g[c];
        float y = (vin[j] - m) * sc + bt[c];
        o[j] = y > 0.f ? y : 0.f;
    }
    if (BF16OUT) {
        ushort4 w;
        w.x = f2bf(o[0]); w.y = f2bf(o[1]); w.z = f2bf(o[2]); w.w = f2bf(o[3]);
        reinterpret_cast<ushort4*>(dst)[i] = w;
    } else {
        float4 w = {o[0], o[1], o[2], o[3]};
        reinterpret_cast<float4*>(dst)[i] = w;
    }
}

// ---------------------------------------------------------------------------
extern "C" void kernel_launch(void* const* d_in, const int* in_sizes, int n_in,
                              void* d_out, int out_size, void* d_ws, size_t ws_size,
                              hipStream_t stream)
{
    const float* x      = (const float*)d_in[0];
    const float* x_skip = (const float*)d_in[1];
    const float* w_up   = (const float*)d_in[2];
    // d_in[3] = b_up cancels exactly through train-mode BN -> unused.
    const float* g_up   = (const float*)d_in[4];
    const float* bt_up  = (const float*)d_in[5];
    const float* w1     = (const float*)d_in[6];
    const float* g1     = (const float*)d_in[7];
    const float* bt1    = (const float*)d_in[8];
    const float* w2     = (const float*)d_in[9];
    const float* g2     = (const float*)d_in[10];
    const float* bt2    = (const float*)d_in[11];
    const int* up_in    = (const int*)d_in[12];
    const int* up_out   = (const int*)d_in[13];
    const int* c1_in    = (const int*)d_in[14];
    const int* c1_out   = (const int*)d_in[15];
    const int* c2_in    = (const int*)d_in[16];
    const int* c2_out   = (const int*)d_in[17];

    // workspace carve (all 16B-aligned)
    ushort* h16    = (ushort*)d_ws;                       // [400000*32]
    ushort* xb16   = h16  + (size_t)N_OUT_C * 32;         // [100000*64]
    ushort* skip16 = xb16 + (size_t)N_IN_C * 64;          // [400000*32]
    ushort* wfU    = skip16 + (size_t)N_OUT_C * 32;       // 27*4*64*8
    ushort* wf1    = wfU + 27 * 4 * 64 * 8;
    ushort* wf2    = wf1 + 27 * 4 * 64 * 8;               // 27*2*64*8
    float*  stats  = (float*)(wf2 + 27 * 2 * 64 * 8);     // 192
    u32*    cnt    = (u32*)(stats + 192);                 // [NB]
    u32*    starts = cnt + NB;                            // [NB+1]
    u32*    cursor = starts + NB + 1;                     // [NB]
    u32*    entries= cursor + NB;                         // [MAXPAIR]

    float* out = (float*)d_out;
    const dim3 blk(256);
    const dim3 gUp((M_UP_C + 255) / 256, KTAPS);
    const dim3 gC ((M_C_C  + 255) / 256, KTAPS);
    const int bn_blocks = (N_OUT_C * 8 + 255) / 256;

    hipMemsetAsync(stats, 0, 192 * sizeof(float), stream);

    // prep: bf16 copies of gather sources + weight fragments
    cvt_bf16_kernel<<<(N_IN_C * 16 + 255) / 256, blk, 0, stream>>>(x, xb16, N_IN_C * 16);
    cvt_bf16_kernel<<<(N_OUT_C * 8 + 255) / 256, blk, 0, stream>>>(x_skip, skip16, N_OUT_C * 8);
    wpack_kernel<<<(17280 + 255) / 256, blk, 0, stream>>>(w_up, w1, w2, wfU, wf1, wf2);

    // ---- stage 1: up conv  (Cin=64 from xb16) -> d_out raw, BN+ReLU -> h16
    hipMemsetAsync(cnt, 0, NB * sizeof(u32), stream);
    hist_kernel<<<gUp, blk, 0, stream>>>(up_out, cnt, M_UP_C);
    scan_kernel<<<1, 1024, 0, stream>>>(cnt, starts, cursor, NB);
    fill_kernel<<<gUp, blk, 0, stream>>>(up_in, up_out, cursor, entries, M_UP_C);
    conv_mfma<4, false><<<NTILES, blk, 0, stream>>>(
        xb16, 64, xb16, 64, wfU, entries, starts, out, stats, N_OUT_C);
    bn_relu_kernel<true><<<bn_blocks, blk, 0, stream>>>(out, stats, g_up, bt_up, h16, N_OUT_C);

    // ---- stage 2: conv1 (Cin=64 = concat(h16, skip16)) -> d_out raw, BN+ReLU -> h16
    hipMemsetAsync(cnt, 0, NB * sizeof(u32), stream);
    hist_kernel<<<gC, blk, 0, stream>>>(c1_out, cnt, M_C_C);
    scan_kernel<<<1, 1024, 0, stream>>>(cnt, starts, cursor, NB);
    fill_kernel<<<gC, blk, 0, stream>>>(c1_in, c1_out, cursor, entries, M_C_C);
    conv_mfma<4, true><<<NTILES, blk, 0, stream>>>(
        h16, 32, skip16, 32, wf1, entries, starts, out, stats + 64, N_OUT_C);
    bn_relu_kernel<true><<<bn_blocks, blk, 0, stream>>>(out, stats + 64, g1, bt1, h16, N_OUT_C);

    // ---- stage 3: conv2 (Cin=32 from h16) -> d_out raw, BN+ReLU in place (f32)
    hipMemsetAsync(cnt, 0, NB * sizeof(u32), stream);
    hist_kernel<<<gC, blk, 0, stream>>>(c2_out, cnt, M_C_C);
    scan_kernel<<<1, 1024, 0, stream>>>(cnt, starts, cursor, NB);
    fill_kernel<<<gC, blk, 0, stream>>>(c2_in, c2_out, cursor, entries, M_C_C);
    conv_mfma<2, false><<<NTILES, blk, 0, stream>>>(
        h16, 32, h16, 32, wf2, entries, starts, out, stats + 128, N_OUT_C);
    bn_relu_kernel<false><<<bn_blocks, blk, 0, stream>>>(out, stats + 128, g2, bt2, out, N_OUT_C);
}